// Round 3
// baseline (99.921 us; speedup 1.0000x reference)
//
#include <hip/hip_runtime.h>

#define BB 16
#define CC 80
#define HWs 16384           // H*W
#define KK 100
#define PCAP 256            // per-plane survivor slot (expected ~110-160)
#define MAXC 3072           // per-plane LDS peak capacity (~1820 expected)
#define NB1 4096            // K1 ordered-key histogram bins (key >> 20)
#define NBINS2 4096         // K2 sigmoid-bits histogram bins

__device__ __forceinline__ unsigned okey(float f) {
    unsigned u = __float_as_uint(f);
    return (u & 0x80000000u) ? ~u : (u | 0x80000000u);
}
__device__ __forceinline__ float okey_inv(unsigned k) {
    unsigned u = (k & 0x80000000u) ? (k & 0x7FFFFFFFu) : ~k;
    return __uint_as_float(u);
}

// One block per (b,c) plane. 18 rows/thread prefetched into registers (deep
// MLP), separable 3x3 max on raw logits, per-plane top-100 cutoff via
// 4096-bin ordered-key histogram, survivors -> private per-plane slot.
__global__ __launch_bounds__(256) void nms_kernel(const float* __restrict__ hm,
                                                  unsigned long long* __restrict__ cand,
                                                  int* __restrict__ cnt) {
    __shared__ int hist[NB1];              // 16 KB
    __shared__ unsigned ckey[MAXC];        // 12 KB
    __shared__ unsigned short cpos[MAXC];  // 6 KB
    __shared__ int red[256];
    __shared__ int s_ncand, s_cut, s_w;

    const int plane = blockIdx.x;          // b*CC + c
    const int c = plane - (plane / CC) * CC;
    const int t = threadIdx.x;
    const int lane = t & 63;
    const int sx = t & 31;                 // 4-wide column strip
    const int x0 = sx << 2;
    const int ys = (t >> 5) << 4;          // 8 bands x 16 rows
    const float4* __restrict__ src4 =
        reinterpret_cast<const float4*>(hm + (size_t)plane * HWs);

    for (int i = t; i < NB1; i += 256) hist[i] = 0;
    if (t == 0) { s_ncand = 0; s_cut = 0; s_w = 0; }
    __syncthreads();

    // prefetch all 18 rows (clamped) -> 18 outstanding loads per lane
    float4 v[18];
#pragma unroll
    for (int r = 0; r < 18; ++r) {
        int rr = ys - 1 + r;
        rr = rr < 0 ? 0 : (rr > 127 ? 127 : rr);
        v[r] = src4[(rr << 5) + sx];
    }

    auto hmax3 = [&](const float4& a) -> float4 {
        float vm1 = __shfl_up(a.w, 1, 32);
        float vp4 = __shfl_down(a.x, 1, 32);
        if (sx == 0) vm1 = a.x;            // SAME padding (clamp)
        if (sx == 31) vp4 = a.w;
        float4 h;
        h.x = fmaxf(fmaxf(vm1, a.x), a.y);
        h.y = fmaxf(fmaxf(a.x, a.y), a.z);
        h.z = fmaxf(fmaxf(a.y, a.z), a.w);
        h.w = fmaxf(fmaxf(a.z, a.w), vp4);
        return h;
    };

    float4 hm1 = hmax3(v[0]);
    float4 h0  = hmax3(v[1]);
#pragma unroll
    for (int r = 0; r < 16; ++r) {
        float4 hp1 = hmax3(v[r + 2]);
        float mm[4], vv[4];
        mm[0] = fmaxf(fmaxf(hm1.x, h0.x), hp1.x);
        mm[1] = fmaxf(fmaxf(hm1.y, h0.y), hp1.y);
        mm[2] = fmaxf(fmaxf(hm1.z, h0.z), hp1.z);
        mm[3] = fmaxf(fmaxf(hm1.w, h0.w), hp1.w);
        vv[0] = v[r + 1].x; vv[1] = v[r + 1].y;
        vv[2] = v[r + 1].z; vv[3] = v[r + 1].w;
#pragma unroll
        for (int j = 0; j < 4; ++j) {
            bool peak = (vv[j] >= mm[j]);  // == max-of-9 incl. self
            unsigned long long mask = __ballot(peak);
            if (mask) {                    // wave-uniform
                int leader = __ffsll(mask) - 1;
                int base = 0;
                if (lane == leader) base = atomicAdd(&s_ncand, __popcll(mask));
                base = __shfl(base, leader, 64);
                if (peak) {
                    int slot = base + __popcll(mask & ((1ull << lane) - 1));
                    unsigned k = okey(vv[j]);
                    if (slot < MAXC) {
                        ckey[slot] = k;
                        cpos[slot] = (unsigned short)(((ys + r) << 7) | (x0 + j));
                    }
                    atomicAdd(&hist[k >> 20], 1);
                }
            }
        }
        hm1 = h0; h0 = hp1;
    }
    __syncthreads();
    int ncand = s_ncand; if (ncand > MAXC) ncand = MAXC;

    // suffix scan: red[t] = # peaks in bins >= 16t
    int chunk = 0;
#pragma unroll
    for (int j = 0; j < 16; ++j) chunk += hist[(t << 4) + j];
    red[t] = chunk;
    __syncthreads();
    for (int off = 1; off < 256; off <<= 1) {
        int vv2 = (t + off < 256) ? red[t + off] : 0;
        __syncthreads();
        red[t] += vv2;
        __syncthreads();
    }
    if (red[0] > KK) {
        int running = (t < 255) ? red[t + 1] : 0;
        if (red[t] >= KK && running < KK) {        // exactly one thread
            for (int j = 15; j >= 0; --j) {        // largest bin w/ suffix >= KK
                running += hist[(t << 4) + j];
                if (running >= KK) { s_cut = (t << 4) + j; break; }
            }
        }
    }
    __syncthreads();
    const unsigned cutkey = (unsigned)s_cut << 20;

    // emit survivors to private plane slot (order irrelevant: K2 sorts)
    unsigned long long* __restrict__ cb = cand + (size_t)plane * PCAP;
    for (int i = t; i < ncand; i += 256) {
        unsigned k = ckey[i];
        if (k >= cutkey) {
            int slot = atomicAdd(&s_w, 1);
            if (slot < PCAP) {
                float lv = okey_inv(k);                 // exact logit bits
                float s = 1.0f / (1.0f + expf(-lv));    // sigmoid only here
                unsigned idx = ((unsigned)c << 14) | (unsigned)cpos[i];
                cb[slot] = ((unsigned long long)__float_as_uint(s) << 32) | idx;
            }
        }
    }
    __syncthreads();
    if (t == 0) cnt[plane] = s_w < PCAP ? s_w : PCAP;
}

// One block per batch: exact top-100 with lax.top_k tie semantics
// (descending score, ties -> lower flat index first), then gather + emit.
__global__ __launch_bounds__(256) void topk_kernel(const unsigned long long* __restrict__ cand,
                                                   const int* __restrict__ cnt,
                                                   const float* __restrict__ bbox,
                                                   const float* __restrict__ offs,
                                                   const int* __restrict__ image_id,
                                                   float* __restrict__ out) {
    __shared__ int hist[NBINS2];               // 16 KB
    __shared__ int csum[256];
    __shared__ unsigned long long list[2048];  // 16 KB
    __shared__ int pcnt[CC];
    __shared__ int s_cut, s_nsel;

    const int b = blockIdx.x;
    const int t = threadIdx.x;

    for (int i = t; i < NBINS2; i += 256) hist[i] = 0;
    if (t < CC) pcnt[t] = cnt[b * CC + t];
    if (t == 0) { s_cut = 0; s_nsel = 0; }
    __syncthreads();

    const unsigned long long* __restrict__ cb = cand + (size_t)b * CC * PCAP;

    // pass 1: histogram (thread t owns entry t of each plane slot)
    for (int p = 0; p < CC; ++p) {
        if (t < pcnt[p]) {
            float s = __uint_as_float((unsigned)(cb[p * PCAP + t] >> 32));
            int bin = (int)(s * (float)NBINS2);
            bin = bin > NBINS2 - 1 ? NBINS2 - 1 : bin;
            atomicAdd(&hist[bin], 1);
        }
    }
    __syncthreads();

    int chunk = 0;
#pragma unroll
    for (int j = 0; j < 16; ++j) chunk += hist[t * 16 + j];
    csum[t] = chunk;
    __syncthreads();
    for (int off = 1; off < 256; off <<= 1) {
        int v = (t + off < 256) ? csum[t + off] : 0;
        __syncthreads();
        csum[t] += v;
        __syncthreads();
    }
    if (csum[0] > KK) {
        int running = (t < 255) ? csum[t + 1] : 0;
        if (csum[t] >= KK && running < KK) {
            for (int j = 15; j >= 0; --j) {
                running += hist[t * 16 + j];
                if (running >= KK) { s_cut = t * 16 + j; break; }
            }
        }
    }
    __syncthreads();
    const int cut = s_cut;

    // pass 2: collect; key = (score_bits << 32) | ~idx -> desc sort gives
    // score desc, index asc on ties (== lax.top_k)
    for (int p = 0; p < CC; ++p) {
        if (t < pcnt[p]) {
            unsigned long long cv = cb[p * PCAP + t];
            float s = __uint_as_float((unsigned)(cv >> 32));
            int bin = (int)(s * (float)NBINS2);
            bin = bin > NBINS2 - 1 ? NBINS2 - 1 : bin;
            if (bin >= cut) {
                int slot = atomicAdd(&s_nsel, 1);
                if (slot < 2048) list[slot] = cv ^ 0xFFFFFFFFull;
            }
        }
    }
    __syncthreads();
    int nsel = s_nsel; if (nsel > 2048) nsel = 2048;

    int P = 128;
    while (P < nsel) P <<= 1;
    for (int i = nsel + t; i < P; i += 256) list[i] = 0ull;
    __syncthreads();

    for (int ksz = 2; ksz <= P; ksz <<= 1) {
        for (int j = ksz >> 1; j > 0; j >>= 1) {
            for (int i = t; i < P; i += 256) {
                int ixj = i ^ j;
                if (ixj > i) {
                    unsigned long long a = list[i], bb2 = list[ixj];
                    bool desc = ((i & ksz) == 0);
                    if (desc ? (a < bb2) : (a > bb2)) { list[i] = bb2; list[ixj] = a; }
                }
            }
            __syncthreads();
        }
    }

    if (t < KK) {
        float s = 0.0f; unsigned idx = 0;
        if (t < nsel) {
            unsigned long long cv = list[t] ^ 0xFFFFFFFFull;
            s = __uint_as_float((unsigned)(cv >> 32));
            idx = (unsigned)(cv & 0xFFFFFFFFu);
        }
        unsigned sp = idx & (HWs - 1);
        float cls = (float)(idx >> 14);
        float ysf = (float)(sp >> 7);
        float xsf = (float)(sp & 127);
        const float* __restrict__ ob  = offs + (size_t)b * 2 * HWs;
        const float* __restrict__ bbx = bbox + (size_t)b * 2 * HWs;
        float cx = xsf + ob[sp];
        float cy = ysf + ob[HWs + sp];
        float w = bbx[sp];
        float h = bbx[HWs + sp];
        float* row = out + ((size_t)b * KK + t) * 7;
        row[0] = (float)image_id[b];
        row[1] = (cx - w * 0.5f) * 4.0f;
        row[2] = (cy - h * 0.5f) * 4.0f;
        row[3] = (cx + w * 0.5f) * 4.0f;
        row[4] = (cy + h * 0.5f) * 4.0f;
        row[5] = s;
        row[6] = cls;
    }
}

extern "C" void kernel_launch(void* const* d_in, const int* in_sizes, int n_in,
                              void* d_out, int out_size, void* d_ws, size_t ws_size,
                              hipStream_t stream) {
    const float* hm      = (const float*)d_in[0];
    const float* bbox    = (const float*)d_in[1];
    const float* offset  = (const float*)d_in[2];
    const int*   img_id  = (const int*)d_in[3];
    float* out = (float*)d_out;

    int* cnt = (int*)d_ws;                                   // 1280 ints
    unsigned long long* cand =
        (unsigned long long*)((char*)d_ws + 8192);           // 1280*256*8 = 2.62 MB

    nms_kernel<<<BB * CC, 256, 0, stream>>>(hm, cand, cnt);
    topk_kernel<<<BB, 256, 0, stream>>>(cand, cnt, bbox, offset, img_id, out);
}